// Round 4
// baseline (693.027 us; speedup 1.0000x reference)
//
#include <hip/hip_runtime.h>
#include <math.h>

// Problem: factor [65536, 2048] fp32.
//   f = row-L2-normalize(factor)  (torch F.normalize, eps=1e-12)
//   adj[i] = <f_i, f_{i+1}>, out = -WEIGHT * 2 * mean(adj)   (single fp32 scalar)
//
// Round-4: same experiment as round 3 (which never ran: container failed) in
// maximally-conservative form. Theory: all VGPR-returning load variants pin
// pass1 at ~1.9 TB/s while the harness's 2-GiB fill writes at 6.4 TB/s; the
// suspected cap is the per-CU vector-load RETURN path. Discriminating change:
// read via global_load_lds (DMA into LDS, no VGPR writeback). This version
// uses ONLY __syncthreads() for ordering (the verified m97 staging pattern):
// no inline asm, no sched_barrier, per-wave-private double buffers.
// Element->lane mapping, FMA order, butterfly order unchanged -> bit-identical.

#define N_ROWS 65536
#define N_COLS 2048
#define RPW 16   // rows per wave; 6.25% boundary re-read; 4096 waves

typedef float v4f __attribute__((ext_vector_type(4)));

// Stage one 8-KiB row into LDS: 8 x (64 lanes x 16 B). LDS dest is
// wave-uniform base + lane*16 (hardware); global src is per-lane.
__device__ __forceinline__ void stage_row(const v4f* __restrict__ rowp, int row,
                                          v4f* lds_base, int lane) {
    const v4f* src = rowp + (long)row * 512 + lane;
    #pragma unroll
    for (int k = 0; k < 8; ++k) {
        __builtin_amdgcn_global_load_lds(
            (const __attribute__((address_space(1))) void*)(src + k * 64),
            (__attribute__((address_space(3))) void*)(lds_base + k * 64),
            16, 0, 0);   // literal size 16 -> global_load_lds_dwordx4
    }
}

__global__ __launch_bounds__(256) void tcr_pass1(const float* __restrict__ x,
                                                 float* __restrict__ sq,
                                                 float* __restrict__ cross) {
    // 4 waves/block x 2 buffers x 512 v4f (8 KiB) = 64 KiB. Buffers are
    // per-wave private; __syncthreads() is used purely as a counter-draining
    // fence (all waves execute identical, uniform control flow).
    __shared__ v4f lds[4][2][512];
    const int wib  = threadIdx.x >> 6;
    const int lane = threadIdx.x & 63;
    const int wid  = (blockIdx.x * 256 + threadIdx.x) >> 6;
    const int r0   = wid * RPW;
    const v4f* __restrict__ rowp = (const v4f*)x;

    // Prologue: rows r0 -> buf0, r0+1 -> buf1 (r0+1 <= 65521 always).
    stage_row(rowp, r0,     &lds[wib][0][0], lane);
    stage_row(rowp, r0 + 1, &lds[wib][1][0], lane);
    __syncthreads();                       // both buffers resident

    v4f A[8], B[8];
    #pragma unroll
    for (int k = 0; k < 8; ++k) A[k] = lds[wib][0][k * 64 + lane];
    __syncthreads();                       // A-reads of buf0 drained before restage

    float sqv[RPW], crv[RPW];

    #pragma unroll
    for (int i = 0; i < RPW; i += 2) {
        // ---- even sub-phase: A = row r0+i (regs); buf1 holds row r0+i+1.
        #pragma unroll
        for (int k = 0; k < 8; ++k) B[k] = lds[wib][1][k * 64 + lane];
        {   // Restage buf0 <- row r0+i+2 (buf0's readers drained last phase).
            int rr = r0 + i + 2; if (rr > N_ROWS - 1) rr = N_ROWS - 1;
            stage_row(rowp, rr, &lds[wib][0][0], lane);
        }
        {   // FMAs consume B -> compiler drains B's ds_reads here (before barrier).
            float s = 0.f, c = 0.f;
            #pragma unroll
            for (int k = 0; k < 8; ++k) {
                s += A[k].x * A[k].x + A[k].y * A[k].y + A[k].z * A[k].z + A[k].w * A[k].w;
                c += A[k].x * B[k].x + A[k].y * B[k].y + A[k].z * B[k].z + A[k].w * B[k].w;
            }
            sqv[i] = s; crv[i] = c;
        }
        __syncthreads();                   // buf0 stage complete; B-reads long done

        // ---- odd sub-phase: B = row r0+i+1 (regs); buf0 holds row r0+i+2.
        #pragma unroll
        for (int k = 0; k < 8; ++k) A[k] = lds[wib][0][k * 64 + lane];
        if (i + 3 <= RPW) {                // rows beyond r0+RPW never needed
            int rr = r0 + i + 3; if (rr > N_ROWS - 1) rr = N_ROWS - 1;
            stage_row(rowp, rr, &lds[wib][1][0], lane);
        }
        {   // FMAs consume A (and B regs) -> A's ds_reads drained here.
            float s = 0.f, c = 0.f;
            #pragma unroll
            for (int k = 0; k < 8; ++k) {
                s += B[k].x * B[k].x + B[k].y * B[k].y + B[k].z * B[k].z + B[k].w * B[k].w;
                c += B[k].x * A[k].x + B[k].y * A[k].y + B[k].z * A[k].z + B[k].w * A[k].w;
            }
            sqv[i + 1] = s; crv[i + 1] = c;
        }
        __syncthreads();                   // buf1 stage complete; A-reads done
    }

    // Batched butterfly: independent 6-step chains, offset order 32..1 per value
    // (same order as the passing kernels -> bit-identical).
    #pragma unroll
    for (int off = 32; off; off >>= 1) {
        #pragma unroll
        for (int i = 0; i < RPW; ++i) {
            sqv[i] += __shfl_xor(sqv[i], off, 64);
            crv[i] += __shfl_xor(crv[i], off, 64);
        }
    }
    if (lane == 0) {
        #pragma unroll
        for (int i = 0; i < RPW; ++i) {
            sq[r0 + i]    = sqv[i];
            cross[r0 + i] = crv[i];   // cross[65535] garbage for last wave; pass2 ignores
        }
    }
}

// Final reduction: sum cross[i] / (max(sqrt(sq[i]),eps) * max(sqrt(sq[i+1]),eps)),
// scale, atomic-accumulate into the fp32 scalar output. fp64 accumulation: the
// sum has heavy cancellation (65535 terms ~±0.02 netting ~0.4). UNCHANGED.
__global__ __launch_bounds__(256) void tcr_pass2(const float* __restrict__ sq,
                                                 const float* __restrict__ cross,
                                                 float* __restrict__ out) {
    const int tid    = blockIdx.x * 256 + threadIdx.x;
    const int stride = gridDim.x * 256;
    double acc = 0.0;
    for (int i = tid; i < N_ROWS - 1; i += stride) {
        double ni = fmax(sqrt((double)sq[i]),     1e-12);
        double nj = fmax(sqrt((double)sq[i + 1]), 1e-12);
        acc += (double)cross[i] / (ni * nj);
    }
    __shared__ double sd[256];
    sd[threadIdx.x] = acc;
    __syncthreads();
    for (int s = 128; s; s >>= 1) {
        if (threadIdx.x < s) sd[threadIdx.x] += sd[threadIdx.x + s];
        __syncthreads();
    }
    if (threadIdx.x == 0) {
        // out = -WEIGHT * (p1 + p2) = -0.01 * 2 * sum/(N-1)
        double partial = sd[0] * (-2.0 * 0.01 / (double)(N_ROWS - 1));
        atomicAdd(out, (float)partial);
    }
}

extern "C" void kernel_launch(void* const* d_in, const int* in_sizes, int n_in,
                              void* d_out, int out_size, void* d_ws, size_t ws_size,
                              hipStream_t stream) {
    const float* factor = (const float*)d_in[0];
    float* out = (float*)d_out;

    // Workspace layout: sq[N_ROWS] floats, then cross[N_ROWS] floats.
    float* sq    = (float*)d_ws;
    float* cross = sq + N_ROWS;

    // Pass 1: 65536 rows / 16 rows-per-wave = 4096 waves = 1024 blocks of 4 waves.
    const int n_waves  = N_ROWS / RPW;
    const int n_blocks = n_waves / 4;
    tcr_pass1<<<n_blocks, 256, 0, stream>>>(factor, sq, cross);

    // Zero the output scalar (harness poisons it to 0xAA before every timed call).
    hipMemsetAsync(d_out, 0, sizeof(float), stream);

    // Pass 2: tiny reduction over 65535 pairs.
    tcr_pass2<<<64, 256, 0, stream>>>(sq, cross, out);
}

// Round 5
// 675.751 us; speedup vs baseline: 1.0256x; 1.0256x over previous
//
#include <hip/hip_runtime.h>
#include <math.h>

// Problem: factor [65536, 2048] fp32.
//   f = row-L2-normalize(factor)  (torch F.normalize, eps=1e-12)
//   adj[i] = <f_i, f_{i+1}>, out = -WEIGHT * 2 * mean(adj)   (single fp32 scalar)
//
// Round-5 theory: the read path is CONCURRENCY-limited. Every prior variant
// (serial, unrolled, nt, LDS-DMA) kept <=8 KiB in flight per wave before a
// cross-FMA dependency drained vmcnt, i.e. <=128 KiB outstanding per CU, and
// all pinned at ~1.9 TB/s; the 6.3 TB/s copy benchmark runs with far more
// aggregate outstanding bytes. Discriminating change: RPW=2, each wave issues
// ALL 24 loads (3 rows, 24 KiB) with zero dependencies in between -> ~16
// waves/CU x 24 KiB ~= 384 KiB in flight per CU (3x prior). Costs 1.5x read
// traffic (786 MB) -- a clear win iff BW scales with concurrency.
// FMA order, butterfly order, pass2 unchanged -> bit-identical output.

#define N_ROWS 65536
#define N_COLS 2048

typedef float v4f __attribute__((ext_vector_type(4)));

__global__ __launch_bounds__(256) void tcr_pass1(const float* __restrict__ x,
                                                 float* __restrict__ sq,
                                                 float* __restrict__ cross) {
    const int wid  = (blockIdx.x * 256 + threadIdx.x) >> 6;   // wave id = row pair
    const int lane = threadIdx.x & 63;
    const int r0   = wid * 2;                                  // rows r0, r0+1 owned
    const v4f* __restrict__ rowp = (const v4f*)x;  // row r = v4f idx [r*512, r*512+512)

    // Row r0+2 clamp: last wave (r0=65534) re-reads row 65535; its cross[65535]
    // is garbage, never read by pass2.
    int r2 = r0 + 2; if (r2 > N_ROWS - 1) r2 = N_ROWS - 1;

    const long bA = (long)r0 * 512 + lane;        // row r0
    const long bB = bA + 512;                     // row r0+1 (r0+1 <= 65535 always)
    const long bC = (long)r2 * 512 + lane;        // row r0+2 (clamped)

    // Issue ALL 24 loads up front: 24 KiB per wave in flight, no dependencies.
    v4f A[8], B[8], C[8];
    #pragma unroll
    for (int k = 0; k < 8; ++k) A[k] = rowp[bA + k * 64];
    #pragma unroll
    for (int k = 0; k < 8; ++k) B[k] = rowp[bB + k * 64];
    #pragma unroll
    for (int k = 0; k < 8; ++k) C[k] = rowp[bC + k * 64];

    // Per-lane partials (same expression order as all passing kernels).
    float s0 = 0.f, c0 = 0.f;   // ||row r0||^2, <row r0, row r0+1>
    #pragma unroll
    for (int k = 0; k < 8; ++k) {
        s0 += A[k].x * A[k].x + A[k].y * A[k].y + A[k].z * A[k].z + A[k].w * A[k].w;
        c0 += A[k].x * B[k].x + A[k].y * B[k].y + A[k].z * B[k].z + A[k].w * B[k].w;
    }
    float s1 = 0.f, c1 = 0.f;   // ||row r0+1||^2, <row r0+1, row r0+2>
    #pragma unroll
    for (int k = 0; k < 8; ++k) {
        s1 += B[k].x * B[k].x + B[k].y * B[k].y + B[k].z * B[k].z + B[k].w * B[k].w;
        c1 += B[k].x * C[k].x + B[k].y * C[k].y + B[k].z * C[k].z + B[k].w * C[k].w;
    }

    // Butterfly reduce, offset order 32..1 per value (bit-identical).
    #pragma unroll
    for (int off = 32; off; off >>= 1) {
        s0 += __shfl_xor(s0, off, 64);
        c0 += __shfl_xor(c0, off, 64);
        s1 += __shfl_xor(s1, off, 64);
        c1 += __shfl_xor(c1, off, 64);
    }
    if (lane == 0) {
        sq[r0]        = s0;
        sq[r0 + 1]    = s1;
        cross[r0]     = c0;
        cross[r0 + 1] = c1;   // garbage for r0+1 == 65535; pass2 ignores
    }
}

// Final reduction: sum cross[i] / (max(sqrt(sq[i]),eps) * max(sqrt(sq[i+1]),eps)),
// scale, atomic-accumulate into the fp32 scalar output. fp64 accumulation: the
// sum has heavy cancellation (65535 terms ~±0.02 netting ~0.4). UNCHANGED.
__global__ __launch_bounds__(256) void tcr_pass2(const float* __restrict__ sq,
                                                 const float* __restrict__ cross,
                                                 float* __restrict__ out) {
    const int tid    = blockIdx.x * 256 + threadIdx.x;
    const int stride = gridDim.x * 256;
    double acc = 0.0;
    for (int i = tid; i < N_ROWS - 1; i += stride) {
        double ni = fmax(sqrt((double)sq[i]),     1e-12);
        double nj = fmax(sqrt((double)sq[i + 1]), 1e-12);
        acc += (double)cross[i] / (ni * nj);
    }
    __shared__ double sd[256];
    sd[threadIdx.x] = acc;
    __syncthreads();
    for (int s = 128; s; s >>= 1) {
        if (threadIdx.x < s) sd[threadIdx.x] += sd[threadIdx.x + s];
        __syncthreads();
    }
    if (threadIdx.x == 0) {
        // out = -WEIGHT * (p1 + p2) = -0.01 * 2 * sum/(N-1)
        double partial = sd[0] * (-2.0 * 0.01 / (double)(N_ROWS - 1));
        atomicAdd(out, (float)partial);
    }
}

extern "C" void kernel_launch(void* const* d_in, const int* in_sizes, int n_in,
                              void* d_out, int out_size, void* d_ws, size_t ws_size,
                              hipStream_t stream) {
    const float* factor = (const float*)d_in[0];
    float* out = (float*)d_out;

    // Workspace layout: sq[N_ROWS] floats, then cross[N_ROWS] floats.
    float* sq    = (float*)d_ws;
    float* cross = sq + N_ROWS;

    // Pass 1: one wave per row pair -> 32768 waves = 8192 blocks of 4 waves.
    const int n_blocks = (N_ROWS / 2) / 4;
    tcr_pass1<<<n_blocks, 256, 0, stream>>>(factor, sq, cross);

    // Zero the output scalar (harness poisons it to 0xAA before every timed call).
    hipMemsetAsync(d_out, 0, sizeof(float), stream);

    // Pass 2: tiny reduction over 65535 pairs.
    tcr_pass2<<<64, 256, 0, stream>>>(sq, cross, out);
}